// Round 1
// baseline (2453.810 us; speedup 1.0000x reference)
//
#include <hip/hip_runtime.h>
#include <stdint.h>

#define BN    32768            // B*N tokens
#define DD    512
#define NE    8
#define TM    64               // tokens per expert tile
#define KCH   64               // K elements per staged weight chunk
#define NKC   8                // 512 / 64
#define CAP   65536            // per-expert routing list capacity (2*BN worst case)
#define LNEPS 1e-5f

typedef __bf16 bf16x8 __attribute__((ext_vector_type(8)));
typedef float  f32x4  __attribute__((ext_vector_type(4)));
typedef unsigned short u16x8 __attribute__((ext_vector_type(8)));

__device__ __forceinline__ uint16_t f2bf(float f){
  union { float f; uint32_t u; } c; c.f = f;
  uint32_t u = c.u;
  u += 0x7FFFu + ((u >> 16) & 1u);          // RNE
  return (uint16_t)(u >> 16);
}

__device__ __forceinline__ void load_lds16(const void* g, void* l){
  __builtin_amdgcn_global_load_lds((__attribute__((address_space(1))) void*)g,
                                   (__attribute__((address_space(3))) void*)l, 16, 0, 0);
}

// ---------------------------------------------------------------------------
// W1[e][k][n] (fp32) -> W1T[e][n][k] (bf16); same for W2. 16 matrices of 512x512.
__global__ void transpose_kernel(const float* __restrict__ W1, const float* __restrict__ W2,
                                 uint16_t* __restrict__ W1T, uint16_t* __restrict__ W2T){
  int mat  = blockIdx.x >> 6;      // 0..15
  int tile = blockIdx.x & 63;      // 8x8 tiles of 64x64
  int tr = (tile >> 3) * 64;       // source row (k)
  int tc = (tile & 7) * 64;        // source col (n)
  const float* src; uint16_t* dst;
  if (mat < 8){ src = W1 + (size_t)mat*DD*DD; dst = W1T + (size_t)mat*DD*DD; }
  else        { src = W2 + (size_t)(mat-8)*DD*DD; dst = W2T + (size_t)(mat-8)*DD*DD; }
  __shared__ float t[64][65];
  int tx = threadIdx.x & 63, ty = threadIdx.x >> 6;   // 64 x 4
  #pragma unroll
  for (int i = 0; i < 16; i++){
    int r = ty*16 + i;
    t[r][tx] = src[(size_t)(tr + r)*DD + tc + tx];
  }
  __syncthreads();
  #pragma unroll
  for (int i = 0; i < 16; i++){
    int r = ty*16 + i;                      // dest row within transposed tile (= source col)
    dst[(size_t)(tc + r)*DD + tr + tx] = f2bf(t[tx][r]);
  }
}

// ---------------------------------------------------------------------------
// Gating: fp64-accumulated scores, top2/bot2 + softmax weights, per-expert lists.
__global__ void gating_kernel(const float* __restrict__ x, const float* __restrict__ Wg,
                              const float* __restrict__ bg, int* __restrict__ cnt,
                              int* __restrict__ tok, float* __restrict__ wgt){
  __shared__ float wg_s[NE*DD];   // transposed: [e][d]
  __shared__ float bg_s[NE];
  int tid = threadIdx.x;
  for (int i = tid; i < DD*NE; i += 256) wg_s[(i & 7)*DD + (i >> 3)] = Wg[i];
  if (tid < NE) bg_s[tid] = bg[tid];
  __syncthreads();
  int wv = tid >> 6, lane = tid & 63;
  int t = blockIdx.x*4 + wv;
  const float* xr = x + (size_t)t*DD;
  double acc[NE];
  #pragma unroll
  for (int e = 0; e < NE; e++) acc[e] = 0.0;
  #pragma unroll
  for (int j = 0; j < 8; j++){
    int d = j*64 + lane;
    double xv = (double)xr[d];
    #pragma unroll
    for (int e = 0; e < NE; e++) acc[e] += xv * (double)wg_s[e*DD + d];
  }
  #pragma unroll
  for (int e = 0; e < NE; e++)
    for (int off = 32; off > 0; off >>= 1) acc[e] += __shfl_down(acc[e], off);
  if (lane == 0){
    float s[NE];
    #pragma unroll
    for (int e = 0; e < NE; e++) s[e] = (float)(acc[e] + (double)bg_s[e]);
    int i1 = 0; for (int e = 1; e < NE; e++) if (s[e] > s[i1]) i1 = e;
    int i2 = -1; for (int e = 0; e < NE; e++){ if (e == i1) continue; if (i2 < 0 || s[e] > s[i2]) i2 = e; }
    int j1 = 0; for (int e = 1; e < NE; e++) if (s[e] < s[j1]) j1 = e;
    int j2 = -1; for (int e = 0; e < NE; e++){ if (e == j1) continue; if (j2 < 0 || s[e] < s[j2]) j2 = e; }
    float et  = expf(s[i2] - s[i1]);                 // <= 1
    float wt1 = 1.f/(1.f + et), wt2 = et/(1.f + et);
    float eb  = expf(s[j1] - s[j2]);                 // <= 1
    float wb1 = eb/(1.f + eb), wb2 = 1.f/(1.f + eb);
    int p;
    p = atomicAdd(&cnt[i1], 1); tok[i1*CAP + p] = t;                           wgt[i1*CAP + p] = wt1;
    p = atomicAdd(&cnt[i2], 1); tok[i2*CAP + p] = t;                           wgt[i2*CAP + p] = wt2;
    p = atomicAdd(&cnt[j1], 1); tok[j1*CAP + p] = (int)((unsigned)t | 0x80000000u); wgt[j1*CAP + p] = wb1;
    p = atomicAdd(&cnt[j2], 1); tok[j2*CAP + p] = (int)((unsigned)t | 0x80000000u); wgt[j2*CAP + p] = wb2;
  }
}

// ---------------------------------------------------------------------------
// Fused expert kernel: per (expert, 64-token tile): X@W1 -> LN -> ReLU -> @W2 -> LN
// -> weighted atomic scatter into out_top / out_bot.
__global__ __launch_bounds__(512, 1) void expert_kernel(
    const float* __restrict__ x,
    const uint16_t* __restrict__ W1T, const uint16_t* __restrict__ W2T,
    const float* __restrict__ b1, const float* __restrict__ ln1w, const float* __restrict__ ln1b,
    const float* __restrict__ b2, const float* __restrict__ ln2w, const float* __restrict__ ln2b,
    const int* __restrict__ cnt, const int* __restrict__ tok, const float* __restrict__ wgt,
    float* __restrict__ out_top, float* __restrict__ out_bot)
{
  int e = blockIdx.y;
  int count = cnt[e];
  int base = blockIdx.x * TM;
  if (base >= count) return;

  extern __shared__ char smem[];
  uint16_t* xh   = (uint16_t*)smem;             // 64KB: X tile, then h1 tile (bf16, swizzled)
  uint16_t* wbuf = (uint16_t*)(smem + 65536);   // 64KB: weight chunk [n][KCH] (bf16, swizzled)
  float* s_sum = (float*)(smem + 131072);       // 64 floats
  float* s_ssq = (float*)(smem + 131072 + 256);
  int*   s_tok = (int*)  (smem + 131072 + 512);
  float* s_wgt = (float*)(smem + 131072 + 768);

  int tid = threadIdx.x;
  int wv = tid >> 6, lane = tid & 63, quad = lane >> 4, cc = lane & 15;
  const int nb = wv * 64;                       // this wave's output-column base

  if (tid < TM){
    int idx = base + tid;
    int src = (idx < count) ? idx : base;       // pad rows duplicate a valid token
    s_tok[tid] = tok[e*CAP + src];
    s_wgt[tid] = (idx < count) ? wgt[e*CAP + src] : 0.f;
  }
  __syncthreads();

  // ---- stage X tile (gather rows, fp32->bf16, XOR-swizzled 16B granules) ----
  #pragma unroll
  for (int i = 0; i < 8; i++){
    int m = i*8 + wv;
    int sl = lane;                              // 16B granule index within row (0..63)
    int tokm = s_tok[m] & 0x7FFFFFFF;
    const float* src = x + (size_t)tokm*DD + sl*8;
    float4 aa = *(const float4*)src;
    float4 bb = *(const float4*)(src + 4);
    u16x8 hv;
    hv[0]=f2bf(aa.x); hv[1]=f2bf(aa.y); hv[2]=f2bf(aa.z); hv[3]=f2bf(aa.w);
    hv[4]=f2bf(bb.x); hv[5]=f2bf(bb.y); hv[6]=f2bf(bb.z); hv[7]=f2bf(bb.w);
    *(u16x8*)(xh + m*DD + ((sl ^ (m & 7)) << 3)) = hv;
  }
  // (first stage barrier below also covers these LDS writes)

  f32x4 acc[4][4];
  const f32x4 zf = {0.f, 0.f, 0.f, 0.f};

  auto run_gemm = [&](const uint16_t* __restrict__ WT){
    #pragma unroll
    for (int mi = 0; mi < 4; mi++)
      #pragma unroll
      for (int ni = 0; ni < 4; ni++) acc[mi][ni] = zf;
    for (int kc = 0; kc < NKC; kc++){
      const uint16_t* Wb = WT + (size_t)e*DD*DD + kc*KCH;
      #pragma unroll
      for (int i = 0; i < 8; i++){              // stage 64KB chunk via global_load_lds x16B
        int f = i*512 + tid;
        int n = f >> 3, s = f & 7;
        int c8 = s ^ (n & 7);                   // swizzled k-granule held in slot s
        load_lds16(Wb + (size_t)n*DD + c8*8, wbuf + f*8);
      }
      __syncthreads();
      #pragma unroll
      for (int s32 = 0; s32 < 2; s32++){
        bf16x8 af[4], bf[4];
        #pragma unroll
        for (int mi = 0; mi < 4; mi++){
          int m = mi*16 + cc;
          int sl = kc*8 + s32*4 + quad;
          af[mi] = *(const bf16x8*)(xh + m*DD + ((sl ^ (m & 7)) << 3));
        }
        #pragma unroll
        for (int ni = 0; ni < 4; ni++){
          int n = nb + ni*16 + cc;
          int s = s32*4 + quad;
          bf[ni] = *(const bf16x8*)(wbuf + n*64 + ((s ^ (n & 7)) << 3));
        }
        #pragma unroll
        for (int mi = 0; mi < 4; mi++)
          #pragma unroll
          for (int ni = 0; ni < 4; ni++)
            acc[mi][ni] = __builtin_amdgcn_mfma_f32_16x16x32_bf16(af[mi], bf[ni], acc[mi][ni], 0, 0, 0);
      }
      __syncthreads();
    }
  };

  float bi[4], lw[4], lb[4];

  // ==================== GEMM1 + LN1 + ReLU ====================
  run_gemm(W1T);
  #pragma unroll
  for (int ni = 0; ni < 4; ni++){
    int col = nb + ni*16 + cc;
    bi[ni] = b1[e*DD + col]; lw[ni] = ln1w[e*DD + col]; lb[ni] = ln1b[e*DD + col];
  }
  if (tid < 64){ s_sum[tid] = 0.f; s_ssq[tid] = 0.f; }
  __syncthreads();
  #pragma unroll
  for (int mi = 0; mi < 4; mi++){
    #pragma unroll
    for (int i = 0; i < 4; i++){
      float p = 0.f, q = 0.f;
      #pragma unroll
      for (int ni = 0; ni < 4; ni++){
        float v = acc[mi][ni][i] + bi[ni];
        p += v; q += v*v;
      }
      #pragma unroll
      for (int off = 1; off < 16; off <<= 1){ p += __shfl_xor(p, off); q += __shfl_xor(q, off); }
      if (cc == 0){
        int r = mi*16 + quad*4 + i;
        atomicAdd(&s_sum[r], p); atomicAdd(&s_ssq[r], q);
      }
    }
  }
  __syncthreads();
  #pragma unroll
  for (int mi = 0; mi < 4; mi++){
    #pragma unroll
    for (int i = 0; i < 4; i++){
      int r = mi*16 + quad*4 + i;
      float mean = s_sum[r] * (1.f/DD);
      float var  = s_ssq[r] * (1.f/DD) - mean*mean;
      float inv  = rsqrtf(var + LNEPS);
      #pragma unroll
      for (int ni = 0; ni < 4; ni++){
        int col = nb + ni*16 + cc;
        float v = (acc[mi][ni][i] + bi[ni] - mean) * inv * lw[ni] + lb[ni];
        v = fmaxf(v, 0.f);
        int g = col >> 3;
        xh[r*DD + ((g ^ (r & 7)) << 3) + (col & 7)] = f2bf(v);   // h1 over X region
      }
    }
  }
  // next run_gemm's first barrier makes h1 visible before any A-frag read

  // ==================== GEMM2 + LN2 + weighted scatter ====================
  run_gemm(W2T);
  #pragma unroll
  for (int ni = 0; ni < 4; ni++){
    int col = nb + ni*16 + cc;
    bi[ni] = b2[e*DD + col]; lw[ni] = ln2w[e*DD + col]; lb[ni] = ln2b[e*DD + col];
  }
  if (tid < 64){ s_sum[tid] = 0.f; s_ssq[tid] = 0.f; }
  __syncthreads();
  #pragma unroll
  for (int mi = 0; mi < 4; mi++){
    #pragma unroll
    for (int i = 0; i < 4; i++){
      float p = 0.f, q = 0.f;
      #pragma unroll
      for (int ni = 0; ni < 4; ni++){
        float v = acc[mi][ni][i] + bi[ni];
        p += v; q += v*v;
      }
      #pragma unroll
      for (int off = 1; off < 16; off <<= 1){ p += __shfl_xor(p, off); q += __shfl_xor(q, off); }
      if (cc == 0){
        int r = mi*16 + quad*4 + i;
        atomicAdd(&s_sum[r], p); atomicAdd(&s_ssq[r], q);
      }
    }
  }
  __syncthreads();
  #pragma unroll
  for (int mi = 0; mi < 4; mi++){
    #pragma unroll
    for (int i = 0; i < 4; i++){
      int r = mi*16 + quad*4 + i;
      float mean = s_sum[r] * (1.f/DD);
      float var  = s_ssq[r] * (1.f/DD) - mean*mean;
      float inv  = rsqrtf(var + LNEPS);
      int pk = s_tok[r];
      float wq = s_wgt[r];                       // 0 for pad rows -> adds 0
      int tk = pk & 0x7FFFFFFF;
      float* orow = (((unsigned)pk >> 31) ? out_bot : out_top) + (size_t)tk*DD;
      #pragma unroll
      for (int ni = 0; ni < 4; ni++){
        int col = nb + ni*16 + cc;
        float v = (acc[mi][ni][i] + bi[ni] - mean) * inv * lw[ni] + lb[ni];
        atomicAdd(&orow[col], wq * v);
      }
    }
  }
}

// ---------------------------------------------------------------------------
// output = out_top + x; per-batch sum of (out_top-out_bot)^2 for orth loss.
__global__ void finalize_kernel(const float* __restrict__ x, const float* __restrict__ ot,
                                const float* __restrict__ ob, float* __restrict__ outp,
                                float* __restrict__ ssq){
  size_t idx = ((size_t)blockIdx.x*256 + threadIdx.x) * 4;
  float4 t  = *(const float4*)(ot + idx);
  float4 b  = *(const float4*)(ob + idx);
  float4 xv = *(const float4*)(x + idx);
  float4 o; o.x = t.x + xv.x; o.y = t.y + xv.y; o.z = t.z + xv.z; o.w = t.w + xv.w;
  *(float4*)(outp + idx) = o;
  float dx = t.x-b.x, dy = t.y-b.y, dz = t.z-b.z, dw = t.w-b.w;
  float p = dx*dx + dy*dy + dz*dz + dw*dw;
  for (int off = 32; off > 0; off >>= 1) p += __shfl_down(p, off);
  __shared__ float red[4];
  int wv = threadIdx.x >> 6, lane = threadIdx.x & 63;
  if (lane == 0) red[wv] = p;
  __syncthreads();
  if (threadIdx.x == 0) atomicAdd(&ssq[blockIdx.x >> 11], red[0]+red[1]+red[2]+red[3]);
}

__global__ void orth_kernel(const float* __restrict__ ssq, float* __restrict__ o){
  if (threadIdx.x == 0){
    float s = 0.f;
    for (int b = 0; b < 8; b++) s += 1.f/(sqrtf(ssq[b]) + 1e-8f);
    o[0] = s * 0.125f;
  }
}

// ---------------------------------------------------------------------------
extern "C" void kernel_launch(void* const* d_in, const int* in_sizes, int n_in,
                              void* d_out, int out_size, void* d_ws, size_t ws_size,
                              hipStream_t stream){
  const float* x    = (const float*)d_in[0];
  const float* Wg   = (const float*)d_in[1];
  const float* bg   = (const float*)d_in[2];
  const float* W1   = (const float*)d_in[3];
  const float* b1   = (const float*)d_in[4];
  const float* ln1w = (const float*)d_in[5];
  const float* ln1b = (const float*)d_in[6];
  const float* W2   = (const float*)d_in[7];
  const float* b2   = (const float*)d_in[8];
  const float* ln2w = (const float*)d_in[9];
  const float* ln2b = (const float*)d_in[10];

  float* out    = (float*)d_out;
  float* o_top  = out + 16777216;              // B*N*D
  float* o_bot  = out + 33554432;
  float* o_orth = out + 50331648;

  char* ws = (char*)d_ws;
  int*      cnt = (int*)ws;                    // 8 ints
  float*    ssq = (float*)(ws + 32);           // 8 floats
  int*      tok = (int*)(ws + 4096);           // 8 * 65536 ints  (2MB)
  float*    wgt = (float*)(ws + 4096 + 2097152);
  uint16_t* W1T = (uint16_t*)(ws + 8388608);   // 4MB bf16
  uint16_t* W2T = (uint16_t*)(ws + 8388608 + 4194304);

  hipMemsetAsync(d_ws, 0, 64, stream);                              // cnt + ssq
  hipMemsetAsync((char*)d_out + 67108864, 0, 134217728, stream);    // out_top + out_bot

  transpose_kernel<<<1024, 256, 0, stream>>>(W1, W2, W1T, W2T);
  gating_kernel<<<8192, 256, 0, stream>>>(x, Wg, bg, cnt, tok, wgt);
  dim3 eg(1024, 8, 1);
  expert_kernel<<<eg, 512, 132096, stream>>>(x, W1T, W2T, b1, ln1w, ln1b,
                                             b2, ln2w, ln2b, cnt, tok, wgt, o_top, o_bot);
  finalize_kernel<<<16384, 256, 0, stream>>>(x, o_top, o_bot, out, ssq);
  orth_kernel<<<1, 64, 0, stream>>>(ssq, o_orth);
}

// Round 2
// 1016.199 us; speedup vs baseline: 2.4147x; 2.4147x over previous
//
#include <hip/hip_runtime.h>
#include <stdint.h>

#define BN    32768            // B*N tokens
#define DD    512
#define NE    8
#define TM    64               // tokens per expert tile
#define KCH   64               // K elements per staged weight chunk
#define NKC   8                // 512 / 64
#define CAP   65536            // per-expert routing list capacity
#define LNEPS 1e-5f

typedef __bf16 bf16x8 __attribute__((ext_vector_type(8)));
typedef float  f32x4  __attribute__((ext_vector_type(4)));
typedef unsigned short u16x8 __attribute__((ext_vector_type(8)));

__device__ __forceinline__ uint16_t f2bf(float f){
  union { float f; uint32_t u; } c; c.f = f;
  uint32_t u = c.u;
  u += 0x7FFFu + ((u >> 16) & 1u);          // RNE
  return (uint16_t)(u >> 16);
}

__device__ __forceinline__ void load_lds16(const void* g, void* l){
  __builtin_amdgcn_global_load_lds((__attribute__((address_space(1))) void*)g,
                                   (__attribute__((address_space(3))) void*)l, 16, 0, 0);
}

// ---------------------------------------------------------------------------
// W1[e][k][n] (fp32) -> W1T[e][n][k] (bf16); same for W2. 16 matrices of 512x512.
__global__ void transpose_kernel(const float* __restrict__ W1, const float* __restrict__ W2,
                                 uint16_t* __restrict__ W1T, uint16_t* __restrict__ W2T){
  int mat  = blockIdx.x >> 6;      // 0..15
  int tile = blockIdx.x & 63;      // 8x8 tiles of 64x64
  int tr = (tile >> 3) * 64;       // source row (k)
  int tc = (tile & 7) * 64;        // source col (n)
  const float* src; uint16_t* dst;
  if (mat < 8){ src = W1 + (size_t)mat*DD*DD; dst = W1T + (size_t)mat*DD*DD; }
  else        { src = W2 + (size_t)(mat-8)*DD*DD; dst = W2T + (size_t)(mat-8)*DD*DD; }
  __shared__ float t[64][65];
  int tx = threadIdx.x & 63, ty = threadIdx.x >> 6;   // 64 x 4
  #pragma unroll
  for (int i = 0; i < 16; i++){
    int r = ty*16 + i;
    t[r][tx] = src[(size_t)(tr + r)*DD + tc + tx];
  }
  __syncthreads();
  #pragma unroll
  for (int i = 0; i < 16; i++){
    int r = ty*16 + i;                      // dest row within transposed tile (= source col)
    dst[(size_t)(tc + r)*DD + tr + tx] = f2bf(t[tx][r]);
  }
}

// ---------------------------------------------------------------------------
// Gating v2: fp64-accumulated scores (decisions bit-stable vs v1), 64 tokens
// per block, block-aggregated list build: 8 global atomics per block instead
// of 16 per wavefront-token (131072 -> 4096 device atomics total).
__global__ __launch_bounds__(256) void gating_kernel(
    const float* __restrict__ x, const float* __restrict__ Wg,
    const float* __restrict__ bg, int* __restrict__ cnt,
    int* __restrict__ tok, float* __restrict__ wgt){
  __shared__ int   ent_tok[256];
  __shared__ float ent_w[256];
  __shared__ int   ent_e[256];
  __shared__ int   wavecnt[4][8];
  __shared__ int   bbase[8];
  int tid = threadIdx.x, wv = tid >> 6, lane = tid & 63;

  // Per-lane Wg slice in registers: rows d = j*64+lane, all 8 experts.
  // Wg is (D,E) row-major -> each lane reads 32B contiguous per j (coalesced).
  float wreg[8][8];
  #pragma unroll
  for (int j = 0; j < 8; j++){
    const float* wr = Wg + (size_t)(j*64 + lane)*NE;
    float4 a = *(const float4*)wr; float4 b = *(const float4*)(wr + 4);
    wreg[j][0]=a.x; wreg[j][1]=a.y; wreg[j][2]=a.z; wreg[j][3]=a.w;
    wreg[j][4]=b.x; wreg[j][5]=b.y; wreg[j][6]=b.z; wreg[j][7]=b.w;
  }
  float bgs[NE];
  #pragma unroll
  for (int e = 0; e < NE; e++) bgs[e] = bg[e];

  int tbase = blockIdx.x*64 + wv*16;
  for (int tt = 0; tt < 16; tt++){
    int t = tbase + tt;
    const float* xr = x + (size_t)t*DD;
    float xv[8];
    #pragma unroll
    for (int j = 0; j < 8; j++) xv[j] = xr[j*64 + lane];
    double acc[NE];
    #pragma unroll
    for (int e = 0; e < NE; e++) acc[e] = 0.0;
    #pragma unroll
    for (int j = 0; j < 8; j++){
      double xd = (double)xv[j];
      #pragma unroll
      for (int e = 0; e < NE; e++) acc[e] += xd * (double)wreg[j][e];
    }
    #pragma unroll
    for (int e = 0; e < NE; e++)
      #pragma unroll
      for (int off = 32; off; off >>= 1) acc[e] += __shfl_xor(acc[e], off);
    if (lane == 0){
      float s[NE];
      #pragma unroll
      for (int e = 0; e < NE; e++) s[e] = (float)(acc[e] + (double)bgs[e]);
      int i1 = 0; for (int e = 1; e < NE; e++) if (s[e] > s[i1]) i1 = e;
      int i2 = -1; for (int e = 0; e < NE; e++){ if (e == i1) continue; if (i2 < 0 || s[e] > s[i2]) i2 = e; }
      int j1 = 0; for (int e = 1; e < NE; e++) if (s[e] < s[j1]) j1 = e;
      int j2 = -1; for (int e = 0; e < NE; e++){ if (e == j1) continue; if (j2 < 0 || s[e] < s[j2]) j2 = e; }
      float et  = expf(s[i2] - s[i1]);                 // <= 1
      float wt1 = 1.f/(1.f + et), wt2 = et/(1.f + et);
      float eb  = expf(s[j1] - s[j2]);                 // <= 1
      float wb1 = eb/(1.f + eb), wb2 = 1.f/(1.f + eb);
      int eb4 = (wv*16 + tt)*4;
      ent_e[eb4+0] = i1; ent_tok[eb4+0] = t;                                ent_w[eb4+0] = wt1;
      ent_e[eb4+1] = i2; ent_tok[eb4+1] = t;                                ent_w[eb4+1] = wt2;
      ent_e[eb4+2] = j1; ent_tok[eb4+2] = (int)((unsigned)t | 0x80000000u); ent_w[eb4+2] = wb1;
      ent_e[eb4+3] = j2; ent_tok[eb4+3] = (int)((unsigned)t | 0x80000000u); ent_w[eb4+3] = wb2;
    }
  }
  __syncthreads();

  // Rank each of the 256 entries within its expert via per-wave ballots.
  int e = ent_e[tid];
  int rank = 0;
  #pragma unroll
  for (int E = 0; E < NE; E++){
    unsigned long long m = __ballot(e == E);
    if (lane == 0) wavecnt[wv][E] = __popcll(m);
    if (e == E) rank = __popcll(m & ((1ull << lane) - 1ull));
  }
  __syncthreads();
  if (tid < NE){
    int tot = wavecnt[0][tid] + wavecnt[1][tid] + wavecnt[2][tid] + wavecnt[3][tid];
    bbase[tid] = atomicAdd(&cnt[tid], tot);
  }
  __syncthreads();
  int basew = 0;
  for (int w = 0; w < wv; w++) basew += wavecnt[w][e];
  int pos = bbase[e] + basew + rank;
  tok[e*CAP + pos] = ent_tok[tid];
  wgt[e*CAP + pos] = ent_w[tid];
}

// ---------------------------------------------------------------------------
// Fused expert kernel: per (expert, 64-token tile): X@W1 -> LN -> ReLU -> @W2 -> LN
// -> weighted atomic scatter into out_top / out_bot.
__global__ __launch_bounds__(512, 1) void expert_kernel(
    const float* __restrict__ x,
    const uint16_t* __restrict__ W1T, const uint16_t* __restrict__ W2T,
    const float* __restrict__ b1, const float* __restrict__ ln1w, const float* __restrict__ ln1b,
    const float* __restrict__ b2, const float* __restrict__ ln2w, const float* __restrict__ ln2b,
    const int* __restrict__ cnt, const int* __restrict__ tok, const float* __restrict__ wgt,
    float* __restrict__ out_top, float* __restrict__ out_bot)
{
  int e = blockIdx.y;
  int count = cnt[e];
  int base = blockIdx.x * TM;
  if (base >= count) return;

  extern __shared__ char smem[];
  uint16_t* xh   = (uint16_t*)smem;             // 64KB: X tile, then h1 tile (bf16, swizzled)
  uint16_t* wbuf = (uint16_t*)(smem + 65536);   // 64KB: weight chunk [n][KCH] (bf16, swizzled)
  float* s_sum = (float*)(smem + 131072);       // 64 floats
  float* s_ssq = (float*)(smem + 131072 + 256);
  int*   s_tok = (int*)  (smem + 131072 + 512);
  float* s_wgt = (float*)(smem + 131072 + 768);

  int tid = threadIdx.x;
  int wv = tid >> 6, lane = tid & 63, quad = lane >> 4, cc = lane & 15;
  const int nb = wv * 64;                       // this wave's output-column base

  if (tid < TM){
    int idx = base + tid;
    int src = (idx < count) ? idx : base;       // pad rows duplicate a valid token
    s_tok[tid] = tok[e*CAP + src];
    s_wgt[tid] = (idx < count) ? wgt[e*CAP + src] : 0.f;
  }
  __syncthreads();

  // ---- stage X tile (gather rows, fp32->bf16, XOR-swizzled 16B granules) ----
  #pragma unroll
  for (int i = 0; i < 8; i++){
    int m = i*8 + wv;
    int sl = lane;                              // 16B granule index within row (0..63)
    int tokm = s_tok[m] & 0x7FFFFFFF;
    const float* src = x + (size_t)tokm*DD + sl*8;
    float4 aa = *(const float4*)src;
    float4 bb = *(const float4*)(src + 4);
    u16x8 hv;
    hv[0]=f2bf(aa.x); hv[1]=f2bf(aa.y); hv[2]=f2bf(aa.z); hv[3]=f2bf(aa.w);
    hv[4]=f2bf(bb.x); hv[5]=f2bf(bb.y); hv[6]=f2bf(bb.z); hv[7]=f2bf(bb.w);
    *(u16x8*)(xh + m*DD + ((sl ^ (m & 7)) << 3)) = hv;
  }
  // (first stage barrier below also covers these LDS writes)

  f32x4 acc[4][4];
  const f32x4 zf = {0.f, 0.f, 0.f, 0.f};

  auto run_gemm = [&](const uint16_t* __restrict__ WT){
    #pragma unroll
    for (int mi = 0; mi < 4; mi++)
      #pragma unroll
      for (int ni = 0; ni < 4; ni++) acc[mi][ni] = zf;
    for (int kc = 0; kc < NKC; kc++){
      const uint16_t* Wb = WT + (size_t)e*DD*DD + kc*KCH;
      #pragma unroll
      for (int i = 0; i < 8; i++){              // stage 64KB chunk via global_load_lds x16B
        int f = i*512 + tid;
        int n = f >> 3, s = f & 7;
        int c8 = s ^ (n & 7);                   // swizzled k-granule held in slot s
        load_lds16(Wb + (size_t)n*DD + c8*8, wbuf + f*8);
      }
      __syncthreads();
      #pragma unroll
      for (int s32 = 0; s32 < 2; s32++){
        bf16x8 af[4], bf[4];
        #pragma unroll
        for (int mi = 0; mi < 4; mi++){
          int m = mi*16 + cc;
          int sl = kc*8 + s32*4 + quad;
          af[mi] = *(const bf16x8*)(xh + m*DD + ((sl ^ (m & 7)) << 3));
        }
        #pragma unroll
        for (int ni = 0; ni < 4; ni++){
          int n = nb + ni*16 + cc;
          int s = s32*4 + quad;
          bf[ni] = *(const bf16x8*)(wbuf + n*64 + ((s ^ (n & 7)) << 3));
        }
        #pragma unroll
        for (int mi = 0; mi < 4; mi++)
          #pragma unroll
          for (int ni = 0; ni < 4; ni++)
            acc[mi][ni] = __builtin_amdgcn_mfma_f32_16x16x32_bf16(af[mi], bf[ni], acc[mi][ni], 0, 0, 0);
      }
      __syncthreads();
    }
  };

  float bi[4], lw[4], lb[4];

  // ==================== GEMM1 + LN1 + ReLU ====================
  run_gemm(W1T);
  #pragma unroll
  for (int ni = 0; ni < 4; ni++){
    int col = nb + ni*16 + cc;
    bi[ni] = b1[e*DD + col]; lw[ni] = ln1w[e*DD + col]; lb[ni] = ln1b[e*DD + col];
  }
  if (tid < 64){ s_sum[tid] = 0.f; s_ssq[tid] = 0.f; }
  __syncthreads();
  #pragma unroll
  for (int mi = 0; mi < 4; mi++){
    #pragma unroll
    for (int i = 0; i < 4; i++){
      float p = 0.f, q = 0.f;
      #pragma unroll
      for (int ni = 0; ni < 4; ni++){
        float v = acc[mi][ni][i] + bi[ni];
        p += v; q += v*v;
      }
      #pragma unroll
      for (int off = 1; off < 16; off <<= 1){ p += __shfl_xor(p, off); q += __shfl_xor(q, off); }
      if (cc == 0){
        int r = mi*16 + quad*4 + i;
        atomicAdd(&s_sum[r], p); atomicAdd(&s_ssq[r], q);
      }
    }
  }
  __syncthreads();
  #pragma unroll
  for (int mi = 0; mi < 4; mi++){
    #pragma unroll
    for (int i = 0; i < 4; i++){
      int r = mi*16 + quad*4 + i;
      float mean = s_sum[r] * (1.f/DD);
      float var  = s_ssq[r] * (1.f/DD) - mean*mean;
      float inv  = rsqrtf(var + LNEPS);
      #pragma unroll
      for (int ni = 0; ni < 4; ni++){
        int col = nb + ni*16 + cc;
        float v = (acc[mi][ni][i] + bi[ni] - mean) * inv * lw[ni] + lb[ni];
        v = fmaxf(v, 0.f);
        int g = col >> 3;
        xh[r*DD + ((g ^ (r & 7)) << 3) + (col & 7)] = f2bf(v);   // h1 over X region
      }
    }
  }
  // next run_gemm's first barrier makes h1 visible before any A-frag read

  // ==================== GEMM2 + LN2 + weighted scatter ====================
  run_gemm(W2T);
  #pragma unroll
  for (int ni = 0; ni < 4; ni++){
    int col = nb + ni*16 + cc;
    bi[ni] = b2[e*DD + col]; lw[ni] = ln2w[e*DD + col]; lb[ni] = ln2b[e*DD + col];
  }
  if (tid < 64){ s_sum[tid] = 0.f; s_ssq[tid] = 0.f; }
  __syncthreads();
  #pragma unroll
  for (int mi = 0; mi < 4; mi++){
    #pragma unroll
    for (int i = 0; i < 4; i++){
      float p = 0.f, q = 0.f;
      #pragma unroll
      for (int ni = 0; ni < 4; ni++){
        float v = acc[mi][ni][i] + bi[ni];
        p += v; q += v*v;
      }
      #pragma unroll
      for (int off = 1; off < 16; off <<= 1){ p += __shfl_xor(p, off); q += __shfl_xor(q, off); }
      if (cc == 0){
        int r = mi*16 + quad*4 + i;
        atomicAdd(&s_sum[r], p); atomicAdd(&s_ssq[r], q);
      }
    }
  }
  __syncthreads();
  #pragma unroll
  for (int mi = 0; mi < 4; mi++){
    #pragma unroll
    for (int i = 0; i < 4; i++){
      int r = mi*16 + quad*4 + i;
      float mean = s_sum[r] * (1.f/DD);
      float var  = s_ssq[r] * (1.f/DD) - mean*mean;
      float inv  = rsqrtf(var + LNEPS);
      int pk = s_tok[r];
      float wq = s_wgt[r];                       // 0 for pad rows -> adds 0
      int tk = pk & 0x7FFFFFFF;
      float* orow = (((unsigned)pk >> 31) ? out_bot : out_top) + (size_t)tk*DD;
      #pragma unroll
      for (int ni = 0; ni < 4; ni++){
        int col = nb + ni*16 + cc;
        float v = (acc[mi][ni][i] + bi[ni] - mean) * inv * lw[ni] + lb[ni];
        atomicAdd(&orow[col], wq * v);
      }
    }
  }
}

// ---------------------------------------------------------------------------
// output = out_top + x; per-batch sum of (out_top-out_bot)^2 for orth loss.
__global__ void finalize_kernel(const float* __restrict__ x, const float* __restrict__ ot,
                                const float* __restrict__ ob, float* __restrict__ outp,
                                float* __restrict__ ssq){
  size_t idx = ((size_t)blockIdx.x*256 + threadIdx.x) * 4;
  float4 t  = *(const float4*)(ot + idx);
  float4 b  = *(const float4*)(ob + idx);
  float4 xv = *(const float4*)(x + idx);
  float4 o; o.x = t.x + xv.x; o.y = t.y + xv.y; o.z = t.z + xv.z; o.w = t.w + xv.w;
  *(float4*)(outp + idx) = o;
  float dx = t.x-b.x, dy = t.y-b.y, dz = t.z-b.z, dw = t.w-b.w;
  float p = dx*dx + dy*dy + dz*dz + dw*dw;
  for (int off = 32; off > 0; off >>= 1) p += __shfl_down(p, off);
  __shared__ float red[4];
  int wv = threadIdx.x >> 6, lane = threadIdx.x & 63;
  if (lane == 0) red[wv] = p;
  __syncthreads();
  if (threadIdx.x == 0) atomicAdd(&ssq[blockIdx.x >> 11], red[0]+red[1]+red[2]+red[3]);
}

__global__ void orth_kernel(const float* __restrict__ ssq, float* __restrict__ o){
  if (threadIdx.x == 0){
    float s = 0.f;
    for (int b = 0; b < 8; b++) s += 1.f/(sqrtf(ssq[b]) + 1e-8f);
    o[0] = s * 0.125f;
  }
}

// ---------------------------------------------------------------------------
extern "C" void kernel_launch(void* const* d_in, const int* in_sizes, int n_in,
                              void* d_out, int out_size, void* d_ws, size_t ws_size,
                              hipStream_t stream){
  const float* x    = (const float*)d_in[0];
  const float* Wg   = (const float*)d_in[1];
  const float* bg   = (const float*)d_in[2];
  const float* W1   = (const float*)d_in[3];
  const float* b1   = (const float*)d_in[4];
  const float* ln1w = (const float*)d_in[5];
  const float* ln1b = (const float*)d_in[6];
  const float* W2   = (const float*)d_in[7];
  const float* b2   = (const float*)d_in[8];
  const float* ln2w = (const float*)d_in[9];
  const float* ln2b = (const float*)d_in[10];

  float* out    = (float*)d_out;
  float* o_top  = out + 16777216;              // B*N*D
  float* o_bot  = out + 33554432;
  float* o_orth = out + 50331648;

  char* ws = (char*)d_ws;
  int*      cnt = (int*)ws;                    // 8 ints
  float*    ssq = (float*)(ws + 32);           // 8 floats
  int*      tok = (int*)(ws + 4096);           // 8 * 65536 ints  (2MB)
  float*    wgt = (float*)(ws + 4096 + 2097152);
  uint16_t* W1T = (uint16_t*)(ws + 8388608);   // 4MB bf16
  uint16_t* W2T = (uint16_t*)(ws + 8388608 + 4194304);

  hipMemsetAsync(d_ws, 0, 64, stream);                              // cnt + ssq
  hipMemsetAsync((char*)d_out + 67108864, 0, 134217728, stream);    // out_top + out_bot

  transpose_kernel<<<1024, 256, 0, stream>>>(W1, W2, W1T, W2T);
  gating_kernel<<<512, 256, 0, stream>>>(x, Wg, bg, cnt, tok, wgt);
  dim3 eg(1024, 8, 1);
  expert_kernel<<<eg, 512, 132096, stream>>>(x, W1T, W2T, b1, ln1w, ln1b,
                                             b2, ln2w, ln2b, cnt, tok, wgt, o_top, o_bot);
  finalize_kernel<<<16384, 256, 0, stream>>>(x, o_top, o_bot, out, ssq);
  orth_kernel<<<1, 64, 0, stream>>>(ssq, o_orth);
}

// Round 3
// 755.968 us; speedup vs baseline: 3.2459x; 1.3442x over previous
//
#include <hip/hip_runtime.h>
#include <stdint.h>

#define BN    32768            // B*N tokens
#define DD    512
#define NE    8
#define TM    64               // tokens per expert tile
#define KCH   64               // K elements per staged weight chunk
#define NKC   8                // 512 / 64
#define CAP   65536            // per-expert routing list capacity (2*BN worst case)
#define LNEPS 1e-5f

typedef __bf16 bf16x8 __attribute__((ext_vector_type(8)));
typedef float  f32x4  __attribute__((ext_vector_type(4)));
typedef unsigned short u16x8 __attribute__((ext_vector_type(8)));

__device__ __forceinline__ uint16_t f2bf(float f){
  union { float f; uint32_t u; } c; c.f = f;
  uint32_t u = c.u;
  u += 0x7FFFu + ((u >> 16) & 1u);          // RNE
  return (uint16_t)(u >> 16);
}

__device__ __forceinline__ float bf2f(uint16_t h){
  union { uint32_t u; float f; } c; c.u = ((uint32_t)h) << 16; return c.f;
}

__device__ __forceinline__ void load_lds16(const void* g, void* l){
  __builtin_amdgcn_global_load_lds((__attribute__((address_space(1))) void*)g,
                                   (__attribute__((address_space(3))) void*)l, 16, 0, 0);
}

// ---------------------------------------------------------------------------
// W1[e][k][n] (fp32) -> W1T[e][n][k] (bf16); same for W2. 16 matrices of 512x512.
__global__ void transpose_kernel(const float* __restrict__ W1, const float* __restrict__ W2,
                                 uint16_t* __restrict__ W1T, uint16_t* __restrict__ W2T){
  int mat  = blockIdx.x >> 6;      // 0..15
  int tile = blockIdx.x & 63;      // 8x8 tiles of 64x64
  int tr = (tile >> 3) * 64;       // source row (k)
  int tc = (tile & 7) * 64;        // source col (n)
  const float* src; uint16_t* dst;
  if (mat < 8){ src = W1 + (size_t)mat*DD*DD; dst = W1T + (size_t)mat*DD*DD; }
  else        { src = W2 + (size_t)(mat-8)*DD*DD; dst = W2T + (size_t)(mat-8)*DD*DD; }
  __shared__ float t[64][65];
  int tx = threadIdx.x & 63, ty = threadIdx.x >> 6;   // 64 x 4
  #pragma unroll
  for (int i = 0; i < 16; i++){
    int r = ty*16 + i;
    t[r][tx] = src[(size_t)(tr + r)*DD + tc + tx];
  }
  __syncthreads();
  #pragma unroll
  for (int i = 0; i < 16; i++){
    int r = ty*16 + i;                      // dest row within transposed tile (= source col)
    dst[(size_t)(tc + r)*DD + tr + tx] = f2bf(t[tx][r]);
  }
}

// ---------------------------------------------------------------------------
// Gating v3: fp64-accumulated scores, block-aggregated list build, plus the
// inverse map slots[t][4] = e*CAP + pos for {top1,top2,bot1,bot2}.
__global__ __launch_bounds__(256) void gating_kernel(
    const float* __restrict__ x, const float* __restrict__ Wg,
    const float* __restrict__ bg, int* __restrict__ cnt,
    int* __restrict__ tok, float* __restrict__ wgt, int* __restrict__ slots){
  __shared__ int   ent_tok[256];
  __shared__ float ent_w[256];
  __shared__ int   ent_e[256];
  __shared__ int   wavecnt[4][8];
  __shared__ int   bbase[8];
  int tid = threadIdx.x, wv = tid >> 6, lane = tid & 63;

  // Per-lane Wg slice in registers: rows d = j*64+lane, all 8 experts (coalesced 32B).
  float wreg[8][8];
  #pragma unroll
  for (int j = 0; j < 8; j++){
    const float* wr = Wg + (size_t)(j*64 + lane)*NE;
    float4 a = *(const float4*)wr; float4 b = *(const float4*)(wr + 4);
    wreg[j][0]=a.x; wreg[j][1]=a.y; wreg[j][2]=a.z; wreg[j][3]=a.w;
    wreg[j][4]=b.x; wreg[j][5]=b.y; wreg[j][6]=b.z; wreg[j][7]=b.w;
  }
  float bgs[NE];
  #pragma unroll
  for (int e = 0; e < NE; e++) bgs[e] = bg[e];

  int tbase = blockIdx.x*64 + wv*16;
  for (int tt = 0; tt < 16; tt++){
    int t = tbase + tt;
    const float* xr = x + (size_t)t*DD;
    float xv[8];
    #pragma unroll
    for (int j = 0; j < 8; j++) xv[j] = xr[j*64 + lane];
    double acc[NE];
    #pragma unroll
    for (int e = 0; e < NE; e++) acc[e] = 0.0;
    #pragma unroll
    for (int j = 0; j < 8; j++){
      double xd = (double)xv[j];
      #pragma unroll
      for (int e = 0; e < NE; e++) acc[e] += xd * (double)wreg[j][e];
    }
    #pragma unroll
    for (int e = 0; e < NE; e++)
      #pragma unroll
      for (int off = 32; off; off >>= 1) acc[e] += __shfl_xor(acc[e], off);
    if (lane == 0){
      float s[NE];
      #pragma unroll
      for (int e = 0; e < NE; e++) s[e] = (float)(acc[e] + (double)bgs[e]);
      int i1 = 0; for (int e = 1; e < NE; e++) if (s[e] > s[i1]) i1 = e;
      int i2 = -1; for (int e = 0; e < NE; e++){ if (e == i1) continue; if (i2 < 0 || s[e] > s[i2]) i2 = e; }
      int j1 = 0; for (int e = 1; e < NE; e++) if (s[e] < s[j1]) j1 = e;
      int j2 = -1; for (int e = 0; e < NE; e++){ if (e == j1) continue; if (j2 < 0 || s[e] < s[j2]) j2 = e; }
      float et  = expf(s[i2] - s[i1]);                 // <= 1
      float wt1 = 1.f/(1.f + et), wt2 = et/(1.f + et);
      float eb  = expf(s[j1] - s[j2]);                 // <= 1
      float wb1 = eb/(1.f + eb), wb2 = 1.f/(1.f + eb);
      int eb4 = (wv*16 + tt)*4;
      ent_e[eb4+0] = i1; ent_tok[eb4+0] = t;                                ent_w[eb4+0] = wt1;
      ent_e[eb4+1] = i2; ent_tok[eb4+1] = t;                                ent_w[eb4+1] = wt2;
      ent_e[eb4+2] = j1; ent_tok[eb4+2] = (int)((unsigned)t | 0x80000000u); ent_w[eb4+2] = wb1;
      ent_e[eb4+3] = j2; ent_tok[eb4+3] = (int)((unsigned)t | 0x80000000u); ent_w[eb4+3] = wb2;
    }
  }
  __syncthreads();

  // Rank each of the 256 entries within its expert via per-wave ballots.
  int e = ent_e[tid];
  int rank = 0;
  #pragma unroll
  for (int E = 0; E < NE; E++){
    unsigned long long m = __ballot(e == E);
    if (lane == 0) wavecnt[wv][E] = __popcll(m);
    if (e == E) rank = __popcll(m & ((1ull << lane) - 1ull));
  }
  __syncthreads();
  if (tid < NE){
    int tot = wavecnt[0][tid] + wavecnt[1][tid] + wavecnt[2][tid] + wavecnt[3][tid];
    bbase[tid] = atomicAdd(&cnt[tid], tot);
  }
  __syncthreads();
  int basew = 0;
  for (int w = 0; w < wv; w++) basew += wavecnt[w][e];
  int pos = bbase[e] + basew + rank;
  tok[e*CAP + pos] = ent_tok[tid];
  wgt[e*CAP + pos] = ent_w[tid];
  // inverse map: token (blockIdx*64 + tid>>2), entry j = tid&3
  slots[(size_t)(blockIdx.x*64 + (tid >> 2))*4 + (tid & 3)] = e*CAP + pos;
}

// ---------------------------------------------------------------------------
// Fused expert kernel: per (expert, 64-token tile): X@W1 -> LN -> ReLU -> @W2 -> LN
// -> weight-scaled bf16 rows into dense contrib buffer (plain coalesced stores).
__global__ __launch_bounds__(512, 1) void expert_kernel(
    const float* __restrict__ x,
    const uint16_t* __restrict__ W1T, const uint16_t* __restrict__ W2T,
    const float* __restrict__ b1, const float* __restrict__ ln1w, const float* __restrict__ ln1b,
    const float* __restrict__ b2, const float* __restrict__ ln2w, const float* __restrict__ ln2b,
    const int* __restrict__ cnt, const int* __restrict__ tok, const float* __restrict__ wgt,
    uint16_t* __restrict__ contrib)
{
  int e = blockIdx.y;
  int count = cnt[e];
  int base = blockIdx.x * TM;
  if (base >= count) return;
  int pbase = 0;
  for (int e2 = 0; e2 < e; e2++) pbase += cnt[e2];   // dense row base for this expert

  extern __shared__ char smem[];
  uint16_t* xh   = (uint16_t*)smem;             // 64KB: X tile / h1 tile / out tile (bf16, swizzled)
  uint16_t* wbuf = (uint16_t*)(smem + 65536);   // 64KB: weight chunk [n][KCH] (bf16, swizzled)
  float* s_sum = (float*)(smem + 131072);       // 64 floats
  float* s_ssq = (float*)(smem + 131072 + 256);
  int*   s_tok = (int*)  (smem + 131072 + 512);
  float* s_wgt = (float*)(smem + 131072 + 768);

  int tid = threadIdx.x;
  int wv = tid >> 6, lane = tid & 63, quad = lane >> 4, cc = lane & 15;
  const int nb = wv * 64;                       // this wave's output-column base

  if (tid < TM){
    int idx = base + tid;
    int src = (idx < count) ? idx : base;       // pad rows duplicate a valid token
    s_tok[tid] = tok[e*CAP + src];
    s_wgt[tid] = (idx < count) ? wgt[e*CAP + src] : 0.f;
  }
  __syncthreads();

  // ---- stage X tile (gather rows, fp32->bf16, XOR-swizzled 16B granules) ----
  #pragma unroll
  for (int i = 0; i < 8; i++){
    int m = i*8 + wv;
    int sl = lane;                              // 16B granule index within row (0..63)
    int tokm = s_tok[m] & 0x7FFFFFFF;
    const float* src = x + (size_t)tokm*DD + sl*8;
    float4 aa = *(const float4*)src;
    float4 bb = *(const float4*)(src + 4);
    u16x8 hv;
    hv[0]=f2bf(aa.x); hv[1]=f2bf(aa.y); hv[2]=f2bf(aa.z); hv[3]=f2bf(aa.w);
    hv[4]=f2bf(bb.x); hv[5]=f2bf(bb.y); hv[6]=f2bf(bb.z); hv[7]=f2bf(bb.w);
    *(u16x8*)(xh + m*DD + ((sl ^ (m & 7)) << 3)) = hv;
  }
  // (first stage barrier below also covers these LDS writes)

  f32x4 acc[4][4];
  const f32x4 zf = {0.f, 0.f, 0.f, 0.f};

  auto run_gemm = [&](const uint16_t* __restrict__ WT){
    #pragma unroll
    for (int mi = 0; mi < 4; mi++)
      #pragma unroll
      for (int ni = 0; ni < 4; ni++) acc[mi][ni] = zf;
    for (int kc = 0; kc < NKC; kc++){
      const uint16_t* Wb = WT + (size_t)e*DD*DD + kc*KCH;
      #pragma unroll
      for (int i = 0; i < 8; i++){              // stage 64KB chunk via global_load_lds x16B
        int f = i*512 + tid;
        int n = f >> 3, s = f & 7;
        int c8 = s ^ (n & 7);                   // swizzled k-granule held in slot s
        load_lds16(Wb + (size_t)n*DD + c8*8, wbuf + f*8);
      }
      __syncthreads();
      #pragma unroll
      for (int s32 = 0; s32 < 2; s32++){
        bf16x8 af[4], bf[4];
        #pragma unroll
        for (int mi = 0; mi < 4; mi++){
          int m = mi*16 + cc;
          int sl = kc*8 + s32*4 + quad;
          af[mi] = *(const bf16x8*)(xh + m*DD + ((sl ^ (m & 7)) << 3));
        }
        #pragma unroll
        for (int ni = 0; ni < 4; ni++){
          int n = nb + ni*16 + cc;
          int s = s32*4 + quad;
          bf[ni] = *(const bf16x8*)(wbuf + n*64 + ((s ^ (n & 7)) << 3));
        }
        #pragma unroll
        for (int mi = 0; mi < 4; mi++)
          #pragma unroll
          for (int ni = 0; ni < 4; ni++)
            acc[mi][ni] = __builtin_amdgcn_mfma_f32_16x16x32_bf16(af[mi], bf[ni], acc[mi][ni], 0, 0, 0);
      }
      __syncthreads();
    }
  };

  float bi[4], lw[4], lb[4];

  // ==================== GEMM1 + LN1 + ReLU ====================
  run_gemm(W1T);
  #pragma unroll
  for (int ni = 0; ni < 4; ni++){
    int col = nb + ni*16 + cc;
    bi[ni] = b1[e*DD + col]; lw[ni] = ln1w[e*DD + col]; lb[ni] = ln1b[e*DD + col];
  }
  if (tid < 64){ s_sum[tid] = 0.f; s_ssq[tid] = 0.f; }
  __syncthreads();
  #pragma unroll
  for (int mi = 0; mi < 4; mi++){
    #pragma unroll
    for (int i = 0; i < 4; i++){
      float p = 0.f, q = 0.f;
      #pragma unroll
      for (int ni = 0; ni < 4; ni++){
        float v = acc[mi][ni][i] + bi[ni];
        p += v; q += v*v;
      }
      #pragma unroll
      for (int off = 1; off < 16; off <<= 1){ p += __shfl_xor(p, off); q += __shfl_xor(q, off); }
      if (cc == 0){
        int r = mi*16 + quad*4 + i;
        atomicAdd(&s_sum[r], p); atomicAdd(&s_ssq[r], q);
      }
    }
  }
  __syncthreads();
  #pragma unroll
  for (int mi = 0; mi < 4; mi++){
    #pragma unroll
    for (int i = 0; i < 4; i++){
      int r = mi*16 + quad*4 + i;
      float mean = s_sum[r] * (1.f/DD);
      float var  = s_ssq[r] * (1.f/DD) - mean*mean;
      float inv  = rsqrtf(var + LNEPS);
      #pragma unroll
      for (int ni = 0; ni < 4; ni++){
        int col = nb + ni*16 + cc;
        float v = (acc[mi][ni][i] + bi[ni] - mean) * inv * lw[ni] + lb[ni];
        v = fmaxf(v, 0.f);
        int g = col >> 3;
        xh[r*DD + ((g ^ (r & 7)) << 3) + (col & 7)] = f2bf(v);   // h1 over X region
      }
    }
  }
  // next run_gemm's first barrier makes h1 visible before any A-frag read

  // ==================== GEMM2 + LN2 + weighted bf16 store ====================
  run_gemm(W2T);
  #pragma unroll
  for (int ni = 0; ni < 4; ni++){
    int col = nb + ni*16 + cc;
    bi[ni] = b2[e*DD + col]; lw[ni] = ln2w[e*DD + col]; lb[ni] = ln2b[e*DD + col];
  }
  if (tid < 64){ s_sum[tid] = 0.f; s_ssq[tid] = 0.f; }
  __syncthreads();
  #pragma unroll
  for (int mi = 0; mi < 4; mi++){
    #pragma unroll
    for (int i = 0; i < 4; i++){
      float p = 0.f, q = 0.f;
      #pragma unroll
      for (int ni = 0; ni < 4; ni++){
        float v = acc[mi][ni][i] + bi[ni];
        p += v; q += v*v;
      }
      #pragma unroll
      for (int off = 1; off < 16; off <<= 1){ p += __shfl_xor(p, off); q += __shfl_xor(q, off); }
      if (cc == 0){
        int r = mi*16 + quad*4 + i;
        atomicAdd(&s_sum[r], p); atomicAdd(&s_ssq[r], q);
      }
    }
  }
  __syncthreads();
  #pragma unroll
  for (int mi = 0; mi < 4; mi++){
    #pragma unroll
    for (int i = 0; i < 4; i++){
      int r = mi*16 + quad*4 + i;
      float mean = s_sum[r] * (1.f/DD);
      float var  = s_ssq[r] * (1.f/DD) - mean*mean;
      float inv  = rsqrtf(var + LNEPS);
      float wq = s_wgt[r];                       // routing weight folded here
      #pragma unroll
      for (int ni = 0; ni < 4; ni++){
        int col = nb + ni*16 + cc;
        float v = (acc[mi][ni][i] + bi[ni] - mean) * inv * lw[ni] + lb[ni];
        int g = col >> 3;
        xh[r*DD + ((g ^ (r & 7)) << 3) + (col & 7)] = f2bf(wq * v);  // out tile over X region
      }
    }
  }
  __syncthreads();
  // coalesced copy-out: 64 rows x 1KB bf16, de-swizzled
  {
    uint16_t* dst = contrib + (size_t)(pbase + base)*DD;
    #pragma unroll
    for (int i = 0; i < 8; i++){
      int c = i*512 + tid;
      int r = c >> 6, g = c & 63;
      if (base + r < count)
        *(u16x8*)(dst + (size_t)r*DD + g*8) = *(const u16x8*)(xh + r*DD + ((g ^ (r & 7)) << 3));
    }
  }
}

// ---------------------------------------------------------------------------
// Per token: gather its 4 contrib rows, emit out_top/out_bot/output, and a
// per-block (2-token) ssq partial — no atomics anywhere.
__global__ __launch_bounds__(256) void finalize_kernel(
    const float* __restrict__ x, const uint16_t* __restrict__ contrib,
    const int* __restrict__ slots, const int* __restrict__ cnt,
    float* __restrict__ outp, float* __restrict__ o_top, float* __restrict__ o_bot,
    float* __restrict__ partials){
  int pb[NE]; int s = 0;
  #pragma unroll
  for (int e = 0; e < NE; e++){ pb[e] = s; s += cnt[e]; }
  int tid = threadIdx.x, grp = tid >> 7, gl = tid & 127;
  int t = blockIdx.x*2 + grp;
  int4 sl = *(const int4*)(slots + (size_t)t*4);
  size_t off = (size_t)gl*4;
  auto ld4 = [&](int slot)->float4{
    int e = slot >> 16, pos = slot & (CAP-1);
    const uint16_t* p = contrib + (size_t)(pb[e] + pos)*DD + off;
    ushort4 u = *(const ushort4*)p;
    float4 f; f.x = bf2f(u.x); f.y = bf2f(u.y); f.z = bf2f(u.z); f.w = bf2f(u.w);
    return f;
  };
  float4 t1 = ld4(sl.x), t2 = ld4(sl.y), b1 = ld4(sl.z), b2 = ld4(sl.w);
  float4 tp; tp.x = t1.x+t2.x; tp.y = t1.y+t2.y; tp.z = t1.z+t2.z; tp.w = t1.w+t2.w;
  float4 bt; bt.x = b1.x+b2.x; bt.y = b1.y+b2.y; bt.z = b1.z+b2.z; bt.w = b1.w+b2.w;
  float4 xv = *(const float4*)(x + (size_t)t*DD + off);
  float4 o; o.x = tp.x+xv.x; o.y = tp.y+xv.y; o.z = tp.z+xv.z; o.w = tp.w+xv.w;
  *(float4*)(o_top + (size_t)t*DD + off) = tp;
  *(float4*)(o_bot + (size_t)t*DD + off) = bt;
  *(float4*)(outp  + (size_t)t*DD + off) = o;
  float dx = tp.x-bt.x, dy = tp.y-bt.y, dz = tp.z-bt.z, dw = tp.w-bt.w;
  float p = dx*dx + dy*dy + dz*dz + dw*dw;
  #pragma unroll
  for (int off2 = 32; off2 > 0; off2 >>= 1) p += __shfl_down(p, off2);
  __shared__ float red[4];
  int wv = tid >> 6, lane = tid & 63;
  if (lane == 0) red[wv] = p;
  __syncthreads();
  if (tid == 0) partials[blockIdx.x] = red[0]+red[1]+red[2]+red[3];
}

// 16384 partials -> 8 per-batch ssq -> orth loss.
__global__ __launch_bounds__(256) void orth_kernel(const float* __restrict__ partials,
                                                   float* __restrict__ o){
  __shared__ float sb[NE];
  __shared__ float red[4];
  int tid = threadIdx.x, wv = tid >> 6, lane = tid & 63;
  for (int b = 0; b < 8; b++){
    float p = 0.f;
    for (int i = tid; i < 2048; i += 256) p += partials[b*2048 + i];
    #pragma unroll
    for (int off = 32; off > 0; off >>= 1) p += __shfl_down(p, off);
    if (lane == 0) red[wv] = p;
    __syncthreads();
    if (tid == 0) sb[b] = red[0]+red[1]+red[2]+red[3];
    __syncthreads();
  }
  if (tid == 0){
    float s = 0.f;
    for (int b = 0; b < 8; b++) s += 1.f/(sqrtf(sb[b]) + 1e-8f);
    o[0] = s * 0.125f;
  }
}

// ---------------------------------------------------------------------------
extern "C" void kernel_launch(void* const* d_in, const int* in_sizes, int n_in,
                              void* d_out, int out_size, void* d_ws, size_t ws_size,
                              hipStream_t stream){
  const float* x    = (const float*)d_in[0];
  const float* Wg   = (const float*)d_in[1];
  const float* bg   = (const float*)d_in[2];
  const float* W1   = (const float*)d_in[3];
  const float* b1   = (const float*)d_in[4];
  const float* ln1w = (const float*)d_in[5];
  const float* ln1b = (const float*)d_in[6];
  const float* W2   = (const float*)d_in[7];
  const float* b2   = (const float*)d_in[8];
  const float* ln2w = (const float*)d_in[9];
  const float* ln2b = (const float*)d_in[10];

  float* out    = (float*)d_out;
  float* o_top  = out + 16777216;              // B*N*D
  float* o_bot  = out + 33554432;
  float* o_orth = out + 50331648;

  char* ws = (char*)d_ws;
  int*      cnt      = (int*)ws;                         // 32 B
  int*      tok      = (int*)(ws + 4096);                // 2 MB
  float*    wgt      = (float*)(ws + 4096 + 2097152);    // 2 MB
  int*      slots    = (int*)(ws + 4198400);             // 512 KB
  float*    partials = (float*)(ws + 4722688);           // 64 KB
  uint16_t* W1T      = (uint16_t*)(ws + 5242880);        // 4 MB bf16
  uint16_t* W2T      = (uint16_t*)(ws + 9437184);        // 4 MB bf16
  uint16_t* contrib  = (uint16_t*)(ws + 13631488);       // 131072 x 512 bf16 = 128 MB

  hipMemsetAsync(d_ws, 0, 64, stream);                   // cnt

  transpose_kernel<<<1024, 256, 0, stream>>>(W1, W2, W1T, W2T);
  gating_kernel<<<512, 256, 0, stream>>>(x, Wg, bg, cnt, tok, wgt, slots);
  dim3 eg(1024, 8, 1);
  expert_kernel<<<eg, 512, 132096, stream>>>(x, W1T, W2T, b1, ln1w, ln1b,
                                             b2, ln2w, ln2b, cnt, tok, wgt, contrib);
  finalize_kernel<<<16384, 256, 0, stream>>>(x, contrib, slots, cnt, out, o_top, o_bot, partials);
  orth_kernel<<<1, 256, 0, stream>>>(partials, o_orth);
}